// Round 2
// baseline (1813.455 us; speedup 1.0000x reference)
//
#include <hip/hip_runtime.h>
#include <hip/hip_bf16.h>
#include <math.h>

#define L_SEQ 64
#define NB    128
#define EMBD  512
#define HID   256
#define G4    1024      // 4*HID
#define NCOL  2048      // 2 dirs * 4H
#define DDIM  512       // 2*HID
#define MS    (L_SEQ*NB)   // 8192 rows per sentence
#define MTOT  (2*MS)       // 16384 combined rows

typedef __bf16 bf16_t;
typedef bf16_t bf16x4 __attribute__((ext_vector_type(4)));
typedef bf16_t bf16x8 __attribute__((ext_vector_type(8)));
typedef float  floatx4 __attribute__((ext_vector_type(4)));
typedef float  floatx8 __attribute__((ext_vector_type(8)));

__device__ __forceinline__ bf16x8 cvt_bf16x8(floatx8 v) {
    bf16x8 r;
    r[0]=(bf16_t)v[0]; r[1]=(bf16_t)v[1]; r[2]=(bf16_t)v[2]; r[3]=(bf16_t)v[3];
    r[4]=(bf16_t)v[4]; r[5]=(bf16_t)v[5]; r[6]=(bf16_t)v[6]; r[7]=(bf16_t)v[7];
    return r;
}

__device__ __forceinline__ void gload_lds16(const bf16_t* g, bf16_t* l) {
    __builtin_amdgcn_global_load_lds(
        (const __attribute__((address_space(1))) unsigned int*)(g),
        (__attribute__((address_space(3))) unsigned int*)(l), 16, 0, 0);
}

__device__ __forceinline__ float fsigmoid(float x) {
    return __builtin_amdgcn_rcpf(1.0f + __expf(-x));
}
__device__ __forceinline__ float ftanh(float x) {
    return 1.0f - 2.0f * __builtin_amdgcn_rcpf(__expf(2.0f*x) + 1.0f);
}

// Raw workgroup barrier: drain LDS ops only (h ping-pong visibility), skip the
// vmcnt(0) store-ack drain __syncthreads would force.
#define LDS_BARRIER() asm volatile("s_waitcnt lgkmcnt(0)\n\ts_barrier" ::: "memory")

// ---------------------------------------------------------------------------
// Pack kernels
// ---------------------------------------------------------------------------
__global__ __launch_bounds__(256) void k_pack_a(const int* __restrict__ t1,
                                                const int* __restrict__ t2,
                                                const float* __restrict__ emb,
                                                bf16_t* __restrict__ A)
{
    int gid = blockIdx.x*256 + threadIdx.x;
    int row = gid >> 6;
    int k8  = (gid & 63) * 8;
    int tok = (row < MS) ? t1[row] : t2[row - MS];
    floatx8 v = *(const floatx8*)(emb + (size_t)tok*EMBD + k8);
    *(bf16x8*)(A + (size_t)row*EMBD + k8) = cvt_bf16x8(v);
}

__global__ __launch_bounds__(256) void k_pack_b(const float* __restrict__ wih_f,
                                                const float* __restrict__ wih_b,
                                                bf16_t* __restrict__ B)
{
    int gid = blockIdx.x*256 + threadIdx.x;
    int n   = gid >> 6;
    int k8  = (gid & 63) * 8;
    const float* src = (n >= 1024) ? (wih_b + (size_t)(n-1024)*EMBD)
                                   : (wih_f + (size_t)n*EMBD);
    *(bf16x8*)(B + (size_t)n*EMBD + k8) = cvt_bf16x8(*(const floatx8*)(src + k8));
}

__global__ __launch_bounds__(256) void k_pack_whh(const float* __restrict__ whh_f,
                                                  const float* __restrict__ whh_b,
                                                  bf16_t* __restrict__ whhB)
{
    int gid = blockIdx.x*256 + threadIdx.x;
    int r2  = gid >> 5;
    int k8  = (gid & 31) * 8;
    const float* src = (r2 >= 1024) ? (whh_b + (size_t)(r2-1024)*HID)
                                    : (whh_f + (size_t)r2*HID);
    *(bf16x8*)(whhB + (size_t)r2*HID + k8) = cvt_bf16x8(*(const floatx8*)(src + k8));
}

// also zeroes the scan handshake flags (re-zeroed every launch: graph-replay safe)
__global__ __launch_bounds__(256) void k_pack_bias(const float* __restrict__ bih_f,
                                                   const float* __restrict__ bhh_f,
                                                   const float* __restrict__ bih_b,
                                                   const float* __restrict__ bhh_b,
                                                   float* __restrict__ bias,
                                                   unsigned* __restrict__ flags)
{
    int n = blockIdx.x*256 + threadIdx.x;
    bias[n] = (n >= 1024) ? (bih_b[n-1024] + bhh_b[n-1024])
                          : (bih_f[n] + bhh_f[n]);
    if (blockIdx.x == 0 && threadIdx.x < 64) flags[threadIdx.x] = 0u;
}

// ---------------------------------------------------------------------------
// xg GEMM v4 (unchanged): epilogue stores bf16 per-chunk layout
//   xgT[(((s2*8 + ch)*64 + l)*1024 + gcol)*16 + bi],  ch=b>>4, bi=b&15
// ---------------------------------------------------------------------------
__global__ __launch_bounds__(256) void xg_gemm4(const bf16_t* __restrict__ A,
                                                const bf16_t* __restrict__ B,
                                                const float* __restrict__ bias,
                                                bf16_t* __restrict__ xgT)
{
    __shared__ bf16_t As[128*32];
    __shared__ bf16_t Bs[128*32];
    const int tid  = threadIdx.x;
    const int wid  = tid >> 6;
    const int lane = tid & 63;
    const int l15  = lane & 15;
    const int quad = lane >> 4;
    const int m0   = blockIdx.y * 128;
    const int n0   = blockIdx.x * 128;
    const int mw   = (wid & 1) * 64;
    const int nw   = (wid >> 1) * 64;

    float biasv[4];
#pragma unroll
    for (int ni = 0; ni < 4; ++ni) biasv[ni] = bias[n0 + nw + ni*16 + l15];

    const int srow = tid >> 2;
    const int sk8  = (tid & 3) * 8;

    floatx4 acc[4][4] = {};
    for (int kk = 0; kk < EMBD; kk += 32) {
#pragma unroll
        for (int inst = 0; inst < 2; ++inst) {
            gload_lds16(A + (size_t)(m0 + inst*64 + srow)*EMBD + kk + sk8,
                        As + inst*2048 + wid*512);
            gload_lds16(B + (size_t)(n0 + inst*64 + srow)*EMBD + kk + sk8,
                        Bs + inst*2048 + wid*512);
        }
        __syncthreads();
        bf16x8 a[4], b[4];
#pragma unroll
        for (int mi = 0; mi < 4; ++mi)
            a[mi] = *(const bf16x8*)(As + (mw + mi*16 + l15)*32 + quad*8);
#pragma unroll
        for (int ni = 0; ni < 4; ++ni)
            b[ni] = *(const bf16x8*)(Bs + (nw + ni*16 + l15)*32 + quad*8);
#pragma unroll
        for (int mi = 0; mi < 4; ++mi)
#pragma unroll
            for (int ni = 0; ni < 4; ++ni)
                acc[mi][ni] = __builtin_amdgcn_mfma_f32_16x16x32_bf16(
                                  a[mi], b[ni], acc[mi][ni], 0, 0, 0);
        __syncthreads();
    }

    // epilogue: per-chunk transposed bf16 store
    const int sent = blockIdx.y >> 6;       // m = sent*8192 + l*128 + b
    const int l    = blockIdx.y & 63;
    const int dir  = n0 >> 10;              // uniform per block
    const int s2   = sent*2 + dir;
#pragma unroll
    for (int mi = 0; mi < 4; ++mi)
#pragma unroll
        for (int ni = 0; ni < 4; ++ni) {
            int gcol = (n0 & 1023) + nw + ni*16 + l15;
            int b    = mw + mi*16 + quad*4;
            int ch   = b >> 4;
            int bi   = b & 15;
            bf16x4 v;
#pragma unroll
            for (int r = 0; r < 4; ++r) v[r] = (bf16_t)(acc[mi][ni][r] + biasv[ni]);
            *(bf16x4*)(xgT + ((size_t)((s2*8 + ch)*64 + l)*1024 + gcol)*16 + bi) = v;
        }
}

// ---------------------------------------------------------------------------
// LSTM scan v9: pair-split across 64 CUs.
//  v8 post-mortem: step time ~constant vs wave count -> per-CU pipe-SUM bound:
//  weights-stream VMEM (128KB/step) + LDS weight reads (128KB) + h reads
//  (128KB) + VALU + MFMA ~ 11-13k cyc/step on 32 CUs.
//  v9: each (s2,chunk) recurrence splits its 256 units across a PAIR of
//  blocks (half = blockIdx.z). Per block: 128 units x 4 gates, weight slab =
//  256KB = 4g x 8ks x 4regs = 128 AGPR/wave at 8 waves (2 waves/EU, full
//  512-reg file). ALL weights in registers -> zero LDS weight traffic, zero
//  streamed-weight VMEM. Per step the pair exchanges h-halves (4KB each way,
//  frame layout) through L3 with device-scope release/acquire + flag
//  (G16-safe). Partner af loads are issued right after the poll and consumed
//  after the own-half MFMAs -> latency hidden. Numerics identical to v8
//  (same bf16 h, same per-gate f32 accumulation).
// ---------------------------------------------------------------------------
__global__
__attribute__((amdgpu_flat_work_group_size(512, 512), amdgpu_waves_per_eu(2, 2)))
void lstm_scan9(
    const bf16_t* __restrict__ whhB,   // [2][1024][256] bf16
    const bf16_t* __restrict__ xgT,    // per-chunk layout
    float* __restrict__ o1, float* __restrict__ o2,
    bf16_t* __restrict__ hx,           // [64 blocks][2 parity][2048] bf16
    unsigned* __restrict__ flags)      // [64]
{
    __shared__ bf16_t hb[2*2048];      // 2 frames x (16 jb x 16 m x 8) = 8 KB

    const int tid  = threadIdx.x;
    const int wv   = tid >> 6;            // 0..7
    const int lane = tid & 63;
    const int l15  = lane & 15;
    const int quad = lane >> 4;
    const int chunk= blockIdx.x;          // 0..7
    const int s2   = blockIdx.y;          // sent*2 + dr
    const int half = blockIdx.z;          // 0..1 (unit half)
    const int sent = s2 >> 1;
    const int dr   = s2 & 1;
    const int b0   = chunk * 16;
    float* o = sent ? o2 : o1;
    const bf16_t* bb = whhB + (size_t)dr * (1024*HID);

    const int fi = (s2*8 + chunk)*2 + half;
    bf16_t*  myBuf  = hx + (size_t)fi*4096;
    const bf16_t* pBuf = hx + (size_t)(fi^1)*4096;
    unsigned* myFlag = flags + fi;
    const unsigned* pFlag = flags + (fi^1);

    const int jl  = wv*16 + l15;          // local unit 0..127
    const int ownKs = half * 4;           // own h-half covers ks ownKs..ownKs+3
    const int parKs = 4 - ownKs;

    // ---- ALL weights (8 k-slices) into registers. volatile: no remat.
    bf16x8 bwc[4][8];
#pragma unroll
    for (int g = 0; g < 4; ++g) {
        const bf16_t* cp = bb + (size_t)(g*256 + half*128 + jl)*HID + quad*8;
#pragma unroll
        for (int ks = 0; ks < 8; ++ks)
            bwc[g][ks] = *(const volatile bf16x8*)(cp + ks*32);
    }

    float cst[4] = {};
    int pp = 0;

    for (int t = 0; t < L_SEQ; ++t) {
        const int lt = dr ? (L_SEQ-1-t) : t;
        asm volatile("" ::: "memory");   // keep in-loop loads in-loop

        // partner h-half: poll flag, then issue af loads (frame layout)
        bf16x8 pa[4];
        if (t > 0) {
            while (__hip_atomic_load(pFlag, __ATOMIC_ACQUIRE,
                                     __HIP_MEMORY_SCOPE_AGENT) < (unsigned)t)
                __builtin_amdgcn_s_sleep(2);
            const bf16_t* pb = pBuf + ((t-1)&1)*2048;
#pragma unroll
            for (int ksl = 0; ksl < 4; ++ksl)
                pa[ksl] = *(const bf16x8*)(pb + ((ksl*4 + quad)*16 + l15)*8);
        }

        // xg for this step (issued after pa: waiting pa leaves xg in flight)
        bf16x4 xvc[4];
        {
            const bf16_t* xp = xgT + (size_t)((s2*8 + chunk)*64 + lt)*16384;
#pragma unroll
            for (int g = 0; g < 4; ++g)
                xvc[g] = *(const bf16x4*)(xp + (size_t)(g*256 + half*128 + jl)*16
                                          + quad*4);
        }

        floatx4 acc[4] = {};
        if (t > 0) {
            const bf16_t* fr = hb + pp*2048;
            // own-half k-slices from LDS
#pragma unroll
            for (int ksl = 0; ksl < 4; ++ksl) {
                bf16x8 af = *(const bf16x8*)(fr + ((ksl*4 + quad)*16 + l15)*8);
#pragma unroll
                for (int g = 0; g < 4; ++g)
                    acc[g] = __builtin_amdgcn_mfma_f32_16x16x32_bf16(
                                 af, bwc[g][ownKs + ksl], acc[g], 0, 0, 0);
            }
            // partner-half k-slices from global (loads issued at step top)
#pragma unroll
            for (int ksl = 0; ksl < 4; ++ksl) {
#pragma unroll
                for (int g = 0; g < 4; ++g)
                    acc[g] = __builtin_amdgcn_mfma_f32_16x16x32_bf16(
                                 pa[ksl], bwc[g][parKs + ksl], acc[g], 0, 0, 0);
            }
        }

        // epilogue: rows m = quad*4+r, unit jl (global unit = half*128 + jl)
        bf16_t* fw = hb + (pp^1)*2048;
        bf16_t* gw = myBuf + (t&1)*2048;
        float* orow = o + (size_t)(lt*NB + b0)*DDIM + dr*HID + half*128 + jl;
        float hvf[4];
#pragma unroll
        for (int r = 0; r < 4; ++r) {
            const int m = quad*4 + r;
            float gi = acc[0][r] + (float)xvc[0][r];
            float gf = acc[1][r] + (float)xvc[1][r];
            float gg = acc[2][r] + (float)xvc[2][r];
            float go = acc[3][r] + (float)xvc[3][r];
            float cv = fsigmoid(gf)*cst[r] + fsigmoid(gi)*ftanh(gg);
            cst[r] = cv;
            float hv = fsigmoid(go)*ftanh(cv);
            hvf[r] = hv;
            bf16_t hvb = (bf16_t)hv;
            const int idx = ((jl >> 3)*16 + m)*8 + (jl & 7);
            fw[idx] = hvb;          // own LDS frame (next step's own-half af)
            gw[idx] = hvb;          // exchange buffer for partner
        }

        // publish h-half: L2 writeback + ack, then flag (device scope)
        __builtin_amdgcn_fence(__ATOMIC_RELEASE, "agent");
        __hip_atomic_store(myFlag, (unsigned)(t+1), __ATOMIC_RELAXED,
                           __HIP_MEMORY_SCOPE_AGENT);

        // o stores after the flag: excluded from the release drain
#pragma unroll
        for (int r = 0; r < 4; ++r)
            orow[(size_t)(quad*4 + r)*DDIM] = hvf[r];

        LDS_BARRIER();
        pp ^= 1;
    }
}

// ---------------------------------------------------------------------------
// mp1[b,d] = max_l o1[l,b,d]
// ---------------------------------------------------------------------------
__global__ __launch_bounds__(256) void k_mp1(const float* __restrict__ o1,
                                             float* __restrict__ mp1)
{
    int gid = blockIdx.x*256 + threadIdx.x;
    float m = -3.402823466e+38f;
    for (int l = 0; l < L_SEQ; ++l)
        m = fmaxf(m, o1[(size_t)l*(NB*DDIM) + gid]);
    mp1[gid] = m;
}

// ---------------------------------------------------------------------------
// attention + sim (unchanged)
// ---------------------------------------------------------------------------
__global__ __launch_bounds__(256) void k_att(const float* __restrict__ o2,
                                             const float* __restrict__ mp1,
                                             float* __restrict__ sim)
{
    const int b   = blockIdx.x;
    const int tid = threadIdx.x;
    const int l   = tid & 63;
    const int cp  = tid >> 6;
    __shared__ float spart[256];
    __shared__ float satt[64], sexp[64], ssm[64];
    __shared__ float red[256];

    const float* o2b = o2  + (size_t)b*32768;
    const float* mpb = mp1 + b*DDIM;

    float p = 0.0f;
    for (int d = cp*128; d < cp*128 + 128; ++d)
        p += mpb[d] * o2b[d*64 + l];
    spart[tid] = p;
    __syncthreads();
    if (tid < 64)
        satt[tid] = spart[tid] + spart[tid+64] + spart[tid+128] + spart[tid+192];
    __syncthreads();
    if (tid < 64) {
        float mx = satt[0];
        for (int i = 1; i < 64; ++i) mx = fmaxf(mx, satt[i]);
        sexp[tid] = expf(satt[tid] - mx);
    }
    __syncthreads();
    if (tid < 64) {
        float s = 0.0f;
        for (int i = 0; i < 64; ++i) s += sexp[i];
        ssm[tid] = sexp[tid] / s;
    }
    __syncthreads();

    float np0 = 0.0f, np1 = 0.0f;
    for (int l2 = 0; l2 < 64; ++l2) {
        float smv = ssm[l2];
        np0 += smv * o2b[l2*DDIM + tid];
        np1 += smv * o2b[l2*DDIM + tid + 256];
    }
    float diff = fabsf(mpb[tid] - np0) + fabsf(mpb[tid+256] - np1);
    red[tid] = diff;
    __syncthreads();
    for (int s = 128; s > 0; s >>= 1) {
        if (tid < s) red[tid] += red[tid + s];
        __syncthreads();
    }
    if (tid == 0) sim[b] = expf(-red[0]);
}

// ---------------------------------------------------------------------------
// commonWords + masked maxes (unchanged)
// ---------------------------------------------------------------------------
__global__ __launch_bounds__(256) void k_common(
    const int*   __restrict__ t1, const int* __restrict__ t2,
    const float* __restrict__ o1, const float* __restrict__ o2,
    float* __restrict__ e1h, float* __restrict__ e2h)
{
    const int b   = blockIdx.x;
    const int tid = threadIdx.x;
    __shared__ int ss1[64];
    __shared__ int smask[64];
    __shared__ int spos[64];
    __shared__ int sany;
    if (tid == 0) sany = 0;
    if (tid < 64) ss1[tid] = t1[tid*NB + b];
    __syncthreads();
    if (tid < 64) {
        int s2 = t2[tid*NB + b];
        int dmax = -1;
        for (int j = 0; j < 64; ++j)
            if (ss1[j] == s2) dmax = j;
        int mk = (dmax > 1) && (s2 > 0);
        smask[tid] = mk;
        spos[tid]  = dmax < 0 ? 0 : dmax;
        if (mk) sany = 1;
    }
    __syncthreads();
    int has = sany;
#pragma unroll
    for (int half = 0; half < 2; ++half) {
        int dd = tid + half*256;
        float m1 = -3.402823466e+38f, m2 = -3.402823466e+38f;
        for (int i = 0; i < 64; ++i) {
            if (smask[i]) {
                m1 = fmaxf(m1, o1[(size_t)spos[i]*(NB*DDIM) + b*DDIM + dd]);
                m2 = fmaxf(m2, o2[(size_t)i      *(NB*DDIM) + b*DDIM + dd]);
            }
        }
        e1h[b*DDIM + dd] = has ? m1 : 0.0f;
        e2h[b*DDIM + dd] = has ? m2 : 0.0f;
    }
}

// ---------------------------------------------------------------------------
extern "C" void kernel_launch(void* const* d_in, const int* in_sizes, int n_in,
                              void* d_out, int out_size, void* d_ws, size_t ws_size,
                              hipStream_t stream)
{
    (void)in_sizes; (void)n_in; (void)out_size; (void)ws_size;
    const int*   t1    = (const int*)d_in[0];
    const int*   t2    = (const int*)d_in[1];
    const float* emb   = (const float*)d_in[2];
    const float* wih_f = (const float*)d_in[3];
    const float* whh_f = (const float*)d_in[4];
    const float* bih_f = (const float*)d_in[5];
    const float* bhh_f = (const float*)d_in[6];
    const float* wih_b = (const float*)d_in[7];
    const float* whh_b = (const float*)d_in[8];
    const float* bih_b = (const float*)d_in[9];
    const float* bhh_b = (const float*)d_in[10];
    float* out = (float*)d_out;

    char* ws = (char*)d_ws;
    size_t off = 0;
    auto carve = [&](size_t bytes) -> void* {
        void* p = ws + off;
        off = (off + bytes + 255) & ~(size_t)255;
        return p;
    };
    float*    o1    = (float*)carve(sizeof(float)*(size_t)L_SEQ*NB*DDIM);
    float*    o2    = (float*)carve(sizeof(float)*(size_t)L_SEQ*NB*DDIM);
    bf16_t*   whhB  = (bf16_t*)carve(sizeof(bf16_t)*2*1024*HID);
    bf16_t*   Bw    = (bf16_t*)carve(sizeof(bf16_t)*(size_t)NCOL*EMBD);
    float*    bias  = (float*)carve(sizeof(float)*NCOL);
    float*    mp1   = (float*)carve(sizeof(float)*NB*DDIM);
    bf16_t*   hx    = (bf16_t*)carve(sizeof(bf16_t)*64*4096);   // 512 KB exchange
    unsigned* flags = (unsigned*)carve(sizeof(unsigned)*64);
    bf16_t*   xgT   = (bf16_t*)carve(sizeof(bf16_t)*(size_t)MTOT*NCOL);  // 67 MB
    bf16_t*   A     = (bf16_t*)o1;   // A dead before scan writes o1

    hipLaunchKernelGGL(k_pack_a,    dim3(4096), dim3(256), 0, stream, t1, t2, emb, A);
    hipLaunchKernelGGL(k_pack_b,    dim3(512),  dim3(256), 0, stream, wih_f, wih_b, Bw);
    hipLaunchKernelGGL(k_pack_whh,  dim3(256),  dim3(256), 0, stream, whh_f, whh_b, whhB);
    hipLaunchKernelGGL(k_pack_bias, dim3(8),    dim3(256), 0, stream,
                       bih_f, bhh_f, bih_b, bhh_b, bias, flags);

    hipLaunchKernelGGL(xg_gemm4, dim3(16, 128), dim3(256), 0, stream, A, Bw, bias, xgT);

    hipLaunchKernelGGL(lstm_scan9, dim3(8, 4, 2), dim3(512), 0, stream,
                       whhB, xgT, o1, o2, hx, flags);

    hipLaunchKernelGGL(k_mp1,    dim3(256), dim3(256), 0, stream, o1, mp1);
    hipLaunchKernelGGL(k_att,    dim3(128), dim3(256), 0, stream, o2, mp1, out);
    hipLaunchKernelGGL(k_common, dim3(128), dim3(256), 0, stream,
                       t1, t2, o1, o2, out + NB, out + NB + NB*DDIM);
}

// Round 3
// 619.149 us; speedup vs baseline: 2.9289x; 2.9289x over previous
//
#include <hip/hip_runtime.h>
#include <hip/hip_bf16.h>
#include <math.h>

#define L_SEQ 64
#define NB    128
#define EMBD  512
#define HID   256
#define G4    1024      // 4*HID
#define NCOL  2048      // 2 dirs * 4H
#define DDIM  512       // 2*HID
#define MS    (L_SEQ*NB)   // 8192 rows per sentence
#define MTOT  (2*MS)       // 16384 combined rows

typedef __bf16 bf16_t;
typedef bf16_t bf16x4 __attribute__((ext_vector_type(4)));
typedef bf16_t bf16x8 __attribute__((ext_vector_type(8)));
typedef float  floatx4 __attribute__((ext_vector_type(4)));
typedef float  floatx8 __attribute__((ext_vector_type(8)));

__device__ __forceinline__ bf16x8 cvt_bf16x8(floatx8 v) {
    bf16x8 r;
    r[0]=(bf16_t)v[0]; r[1]=(bf16_t)v[1]; r[2]=(bf16_t)v[2]; r[3]=(bf16_t)v[3];
    r[4]=(bf16_t)v[4]; r[5]=(bf16_t)v[5]; r[6]=(bf16_t)v[6]; r[7]=(bf16_t)v[7];
    return r;
}

__device__ __forceinline__ void gload_lds16(const bf16_t* g, bf16_t* l) {
    __builtin_amdgcn_global_load_lds(
        (const __attribute__((address_space(1))) unsigned int*)(g),
        (__attribute__((address_space(3))) unsigned int*)(l), 16, 0, 0);
}

__device__ __forceinline__ float fsigmoid(float x) {
    return __builtin_amdgcn_rcpf(1.0f + __expf(-x));
}
__device__ __forceinline__ float ftanh(float x) {
    return 1.0f - 2.0f * __builtin_amdgcn_rcpf(__expf(2.0f*x) + 1.0f);
}

// Raw workgroup barrier: drain LDS ops only (h ping-pong visibility), skip the
// vmcnt(0) store-ack drain __syncthreads would force (o-stores have no
// intra-kernel consumer; kernel-end drain covers the downstream kernels).
#define LDS_BARRIER() asm volatile("s_waitcnt lgkmcnt(0)\n\ts_barrier" ::: "memory")

// ---------------------------------------------------------------------------
// Pack kernels. k_pack_w merges the three small weight/bias packs into one
// launch (kills two launch gaps; values bitwise identical).
// ---------------------------------------------------------------------------
__global__ __launch_bounds__(256) void k_pack_a(const int* __restrict__ t1,
                                                const int* __restrict__ t2,
                                                const float* __restrict__ emb,
                                                bf16_t* __restrict__ A)
{
    int gid = blockIdx.x*256 + threadIdx.x;
    int row = gid >> 6;
    int k8  = (gid & 63) * 8;
    int tok = (row < MS) ? t1[row] : t2[row - MS];
    floatx8 v = *(const floatx8*)(emb + (size_t)tok*EMBD + k8);
    *(bf16x8*)(A + (size_t)row*EMBD + k8) = cvt_bf16x8(v);
}

__global__ __launch_bounds__(256) void k_pack_w(
    const float* __restrict__ wih_f, const float* __restrict__ wih_b,
    const float* __restrict__ whh_f, const float* __restrict__ whh_b,
    const float* __restrict__ bih_f, const float* __restrict__ bhh_f,
    const float* __restrict__ bih_b, const float* __restrict__ bhh_b,
    bf16_t* __restrict__ B, bf16_t* __restrict__ whhB,
    float* __restrict__ bias)
{
    int gid = blockIdx.x*256 + threadIdx.x;
    if (gid < 131072) {                       // wih pack: 2048 rows x 8 vec8
        int n  = gid >> 6;
        int k8 = (gid & 63) * 8;
        const float* src = (n >= 1024) ? (wih_b + (size_t)(n-1024)*EMBD)
                                       : (wih_f + (size_t)n*EMBD);
        *(bf16x8*)(B + (size_t)n*EMBD + k8) = cvt_bf16x8(*(const floatx8*)(src + k8));
    } else if (gid < 196608) {                // whh pack: 2048 rows x 4 vec8
        int g2 = gid - 131072;
        int r2 = g2 >> 5;
        int k8 = (g2 & 31) * 8;
        const float* src = (r2 >= 1024) ? (whh_b + (size_t)(r2-1024)*HID)
                                        : (whh_f + (size_t)r2*HID);
        *(bf16x8*)(whhB + (size_t)r2*HID + k8) = cvt_bf16x8(*(const floatx8*)(src + k8));
    } else {                                  // bias: 2048 scalars
        int n = gid - 196608;
        bias[n] = (n >= 1024) ? (bih_b[n-1024] + bhh_b[n-1024])
                              : (bih_f[n] + bhh_f[n]);
    }
}

// ---------------------------------------------------------------------------
// xg GEMM v5 = v4 + XCD-aware bijective block swizzle.
//  Grid 2048 blocks (16 N x 128 M); hw dispatch round-robins XCDs, scattering
//  the 16-block family that shares one 128KB A-panel across 8 L2s. Chunked
//  remap gives each XCD a contiguous virt range (16 A-panels + all of B ~ 4MB
//  = its L2). 2048 % 8 == 0 -> simple bijective form.
//  Epilogue stores bf16 per-chunk layout:
//   xgT[(((s2*8 + ch)*64 + l)*1024 + gcol)*16 + bi],  ch=b>>4, bi=b&15
// ---------------------------------------------------------------------------
__global__ __launch_bounds__(256) void xg_gemm4(const bf16_t* __restrict__ A,
                                                const bf16_t* __restrict__ B,
                                                const float* __restrict__ bias,
                                                bf16_t* __restrict__ xgT)
{
    __shared__ bf16_t As[128*32];
    __shared__ bf16_t Bs[128*32];
    const int tid  = threadIdx.x;
    const int wid  = tid >> 6;
    const int lane = tid & 63;
    const int l15  = lane & 15;
    const int quad = lane >> 4;

    // XCD swizzle: hw linear id -> virt id, contiguous per XCD
    const int bid  = blockIdx.y * 16 + blockIdx.x;
    const int virt = (bid & 7) * 256 + (bid >> 3);
    const int bx   = virt & 15;            // N-tile
    const int by   = virt >> 4;            // M-tile
    const int m0   = by * 128;
    const int n0   = bx * 128;
    const int mw   = (wid & 1) * 64;
    const int nw   = (wid >> 1) * 64;

    float biasv[4];
#pragma unroll
    for (int ni = 0; ni < 4; ++ni) biasv[ni] = bias[n0 + nw + ni*16 + l15];

    const int srow = tid >> 2;
    const int sk8  = (tid & 3) * 8;

    floatx4 acc[4][4] = {};
    for (int kk = 0; kk < EMBD; kk += 32) {
#pragma unroll
        for (int inst = 0; inst < 2; ++inst) {
            gload_lds16(A + (size_t)(m0 + inst*64 + srow)*EMBD + kk + sk8,
                        As + inst*2048 + wid*512);
            gload_lds16(B + (size_t)(n0 + inst*64 + srow)*EMBD + kk + sk8,
                        Bs + inst*2048 + wid*512);
        }
        __syncthreads();
        bf16x8 a[4], b[4];
#pragma unroll
        for (int mi = 0; mi < 4; ++mi)
            a[mi] = *(const bf16x8*)(As + (mw + mi*16 + l15)*32 + quad*8);
#pragma unroll
        for (int ni = 0; ni < 4; ++ni)
            b[ni] = *(const bf16x8*)(Bs + (nw + ni*16 + l15)*32 + quad*8);
#pragma unroll
        for (int mi = 0; mi < 4; ++mi)
#pragma unroll
            for (int ni = 0; ni < 4; ++ni)
                acc[mi][ni] = __builtin_amdgcn_mfma_f32_16x16x32_bf16(
                                  a[mi], b[ni], acc[mi][ni], 0, 0, 0);
        __syncthreads();
    }

    // epilogue: per-chunk transposed bf16 store
    const int sent = by >> 6;               // m = sent*8192 + l*128 + b
    const int l    = by & 63;
    const int dir  = n0 >> 10;              // uniform per block
    const int s2   = sent*2 + dir;
#pragma unroll
    for (int mi = 0; mi < 4; ++mi)
#pragma unroll
        for (int ni = 0; ni < 4; ++ni) {
            int gcol = (n0 & 1023) + nw + ni*16 + l15;
            int b    = mw + mi*16 + quad*4;
            int ch   = b >> 4;
            int bi   = b & 15;
            bf16x4 v;
#pragma unroll
            for (int r = 0; r < 4; ++r) v[r] = (bf16_t)(acc[mi][ni][r] + biasv[ni]);
            *(bf16x4*)(xgT + ((size_t)((s2*8 + ch)*64 + l)*1024 + gcol)*16 + bi) = v;
        }
}

// ---------------------------------------------------------------------------
// LSTM scan v8 (reverted verbatim — best known, 363us).
//  v9 post-mortem: pair-splitting a recurrence across blocks with per-step
//  agent-scope release/acquire costs ~20us/step (acquire poll = buffer_inv
//  per iteration, release = L2 writeback; WRITE_SIZE doubled). A recurrence
//  must stay on one CU. v8 is pipe-sum-bound at ~13.6k cyc/step with no
//  single dominant pipe; weight slab (512KB) > VGPR(256KB)+LDS(144KB) makes
//  the ks6/7 stream irreducible.
// ---------------------------------------------------------------------------
__global__
__attribute__((amdgpu_flat_work_group_size(1024, 1024), amdgpu_waves_per_eu(4, 4)))
void lstm_scan8(
    const bf16_t* __restrict__ whhB,   // [2][1024][256] bf16
    const bf16_t* __restrict__ xgT,    // per-chunk layout
    float* __restrict__ o1, float* __restrict__ o2)
{
    extern __shared__ char smem[];
    bf16_t* hb = (bf16_t*)smem;              // 2 frames x 4096 bf16 = 16 KB
    bf16_t* BL = (bf16_t*)(smem + 16384);    // 128 frags x 512 bf16 = 128 KB

    const int tid  = threadIdx.x;
    const int wv   = tid >> 6;            // 0..15
    const int lane = tid & 63;
    const int l15  = lane & 15;
    const int quad = lane >> 4;
    const int s2   = blockIdx.y;          // sent*2 + dr
    const int sent = s2 >> 1;
    const int dr   = s2 & 1;
    const int chunk= blockIdx.x;
    const int b0   = chunk * 16;
    float* o = sent ? o2 : o1;
    const bf16_t* bb = whhB + (size_t)dr * (1024*HID);

    // wave wv owns units j = wv*16 + l15; gate column col(g) = g*256 + wv*16 + l15

    // ---- LDS weight preload: ks 4,5 for all 4 gates of this wave's unit slice
#pragma unroll
    for (int g = 0; g < 4; ++g) {
        const int col = g*256 + wv*16 + l15;
#pragma unroll
        for (int ksl = 0; ksl < 2; ++ksl)
            gload_lds16(bb + (size_t)col*HID + (4+ksl)*32 + quad*8,
                        BL + (size_t)((wv*4 + g)*2 + ksl)*512);
    }

    // ---- VGPR weights ks0..3 — volatile loads: no rematerialization
    bf16x8 bwc[4][4];
#pragma unroll
    for (int g = 0; g < 4; ++g) {
        const bf16_t* cp = bb + (size_t)(g*256 + wv*16 + l15)*HID + quad*8;
#pragma unroll
        for (int ks = 0; ks < 4; ++ks)
            bwc[g][ks] = *(const volatile bf16x8*)(cp + ks*32);
    }

    // zero h frame 0 (legacy safety; frame 0 is never read before first write)
    for (int i = tid; i < 4096; i += 1024) hb[i] = (bf16_t)0.0f;
    __syncthreads();   // full drain once (also covers global_load_lds)

    float cst[4] = {};
    int pp = 0;

    for (int t = 0; t < L_SEQ; ++t) {
        const int lt = dr ? (L_SEQ-1-t) : t;
        asm volatile("" ::: "memory");   // keep in-loop loads in-loop

        // xg for THIS step: issued at top, consumed in epilogue — full MFMA
        // phase of slack to cover L2/L3 latency.
        bf16x4 xvc[4];
        {
            const bf16_t* xp = xgT + (size_t)((s2*8 + chunk)*64 + lt)*16384;
#pragma unroll
            for (int g = 0; g < 4; ++g)
                xvc[g] = *(const bf16x4*)(xp + (size_t)(g*256 + wv*16 + l15)*16
                                          + quad*4);
        }

        floatx4 acc[4] = {};
        if (t > 0) {
            // streamed weight buffer (single 16-reg buffer, used twice)
            bf16x8 sb[4];
#pragma unroll
            for (int g = 0; g < 4; ++g) {
                const bf16_t* cp = bb + (size_t)(g*256 + wv*16 + l15)*HID;
                sb[g] = *(const bf16x8*)(cp + 6*32 + quad*8);
            }

            const bf16_t* fr = hb + pp*4096;
            // ks0..3: VGPR weights
#pragma unroll
            for (int ks = 0; ks < 4; ++ks) {
                bf16x8 af = *(const bf16x8*)(fr + ((ks*4 + quad)*16 + l15)*8);
#pragma unroll
                for (int g = 0; g < 4; ++g)
                    acc[g] = __builtin_amdgcn_mfma_f32_16x16x32_bf16(
                                 af, bwc[g][ks], acc[g], 0, 0, 0);
            }
            // ks6: streamed batch 1 (issued at step top, latency covered)
            {
                bf16x8 af6 = *(const bf16x8*)(fr + ((6*4 + quad)*16 + l15)*8);
#pragma unroll
                for (int g = 0; g < 4; ++g)
                    acc[g] = __builtin_amdgcn_mfma_f32_16x16x32_bf16(
                                 af6, sb[g], acc[g], 0, 0, 0);
            }
            // reissue stream buffer for ks7; ks4,5 (LDS) hide its L2 latency
#pragma unroll
            for (int g = 0; g < 4; ++g) {
                const bf16_t* cp = bb + (size_t)(g*256 + wv*16 + l15)*HID;
                sb[g] = *(const bf16x8*)(cp + 7*32 + quad*8);
            }
            // ks4,5: LDS weights
#pragma unroll
            for (int ksl = 0; ksl < 2; ++ksl) {
                bf16x8 af = *(const bf16x8*)(fr + (((4+ksl)*4 + quad)*16 + l15)*8);
#pragma unroll
                for (int g = 0; g < 4; ++g) {
                    bf16x8 bl = *(const bf16x8*)(BL + (size_t)((wv*4 + g)*2 + ksl)*512
                                                 + lane*8);
                    acc[g] = __builtin_amdgcn_mfma_f32_16x16x32_bf16(
                                 af, bl, acc[g], 0, 0, 0);
                }
            }
            // ks7: streamed batch 2
            {
                bf16x8 af7 = *(const bf16x8*)(fr + ((7*4 + quad)*16 + l15)*8);
#pragma unroll
                for (int g = 0; g < 4; ++g)
                    acc[g] = __builtin_amdgcn_mfma_f32_16x16x32_bf16(
                                 af7, sb[g], acc[g], 0, 0, 0);
            }
        }

        // epilogue: rows m = quad*4+r, unit j = wv*16 + l15
        bf16_t* fw = hb + (pp^1)*4096;
        const int j = wv*16 + l15;
        float* orow = o + (size_t)(lt*NB + b0)*DDIM + dr*HID + j;
#pragma unroll
        for (int r = 0; r < 4; ++r) {
            const int m = quad*4 + r;
            float gi = acc[0][r] + (float)xvc[0][r];
            float gf = acc[1][r] + (float)xvc[1][r];
            float gg = acc[2][r] + (float)xvc[2][r];
            float go = acc[3][r] + (float)xvc[3][r];
            float cv = fsigmoid(gf)*cst[r] + fsigmoid(gi)*ftanh(gg);
            cst[r] = cv;
            float hv = fsigmoid(go)*ftanh(cv);
            orow[(size_t)m*DDIM] = hv;
            fw[((j >> 3)*16 + m)*8 + (j & 7)] = (bf16_t)hv;
        }
        LDS_BARRIER();
        pp ^= 1;
    }
}

// ---------------------------------------------------------------------------
// attention + sim, with mp1 fused in (each block recomputes its own row-max
// in the same l-order as the old k_mp1 -> bitwise identical values; kills one
// launch and the mp1 global round-trip).
// ---------------------------------------------------------------------------
__global__ __launch_bounds__(256) void k_att(const float* __restrict__ o1,
                                             const float* __restrict__ o2,
                                             float* __restrict__ sim)
{
    const int b   = blockIdx.x;
    const int tid = threadIdx.x;
    const int l   = tid & 63;
    const int cp  = tid >> 6;
    __shared__ float smp[512];
    __shared__ float spart[256];
    __shared__ float satt[64], sexp[64], ssm[64];
    __shared__ float red[256];

    const float* o2b = o2 + (size_t)b*32768;

    // fused mp1: smp[d] = max_l o1[l,b,d]
#pragma unroll
    for (int h = 0; h < 2; ++h) {
        const int d = tid + h*256;
        float m = -3.402823466e+38f;
        for (int ll = 0; ll < 64; ++ll)
            m = fmaxf(m, o1[(size_t)ll*(NB*DDIM) + b*DDIM + d]);
        smp[d] = m;
    }
    __syncthreads();

    float p = 0.0f;
    for (int d = cp*128; d < cp*128 + 128; ++d)
        p += smp[d] * o2b[d*64 + l];
    spart[tid] = p;
    __syncthreads();
    if (tid < 64)
        satt[tid] = spart[tid] + spart[tid+64] + spart[tid+128] + spart[tid+192];
    __syncthreads();
    if (tid < 64) {
        float mx = satt[0];
        for (int i = 1; i < 64; ++i) mx = fmaxf(mx, satt[i]);
        sexp[tid] = expf(satt[tid] - mx);
    }
    __syncthreads();
    if (tid < 64) {
        float s = 0.0f;
        for (int i = 0; i < 64; ++i) s += sexp[i];
        ssm[tid] = sexp[tid] / s;
    }
    __syncthreads();

    float np0 = 0.0f, np1 = 0.0f;
    for (int l2 = 0; l2 < 64; ++l2) {
        float smv = ssm[l2];
        np0 += smv * o2b[l2*DDIM + tid];
        np1 += smv * o2b[l2*DDIM + tid + 256];
    }
    float diff = fabsf(smp[tid] - np0) + fabsf(smp[tid+256] - np1);
    red[tid] = diff;
    __syncthreads();
    for (int s = 128; s > 0; s >>= 1) {
        if (tid < s) red[tid] += red[tid + s];
        __syncthreads();
    }
    if (tid == 0) sim[b] = expf(-red[0]);
}

// ---------------------------------------------------------------------------
// commonWords + masked maxes (unchanged)
// ---------------------------------------------------------------------------
__global__ __launch_bounds__(256) void k_common(
    const int*   __restrict__ t1, const int* __restrict__ t2,
    const float* __restrict__ o1, const float* __restrict__ o2,
    float* __restrict__ e1h, float* __restrict__ e2h)
{
    const int b   = blockIdx.x;
    const int tid = threadIdx.x;
    __shared__ int ss1[64];
    __shared__ int smask[64];
    __shared__ int spos[64];
    __shared__ int sany;
    if (tid == 0) sany = 0;
    if (tid < 64) ss1[tid] = t1[tid*NB + b];
    __syncthreads();
    if (tid < 64) {
        int s2 = t2[tid*NB + b];
        int dmax = -1;
        for (int j = 0; j < 64; ++j)
            if (ss1[j] == s2) dmax = j;
        int mk = (dmax > 1) && (s2 > 0);
        smask[tid] = mk;
        spos[tid]  = dmax < 0 ? 0 : dmax;
        if (mk) sany = 1;
    }
    __syncthreads();
    int has = sany;
#pragma unroll
    for (int half = 0; half < 2; ++half) {
        int dd = tid + half*256;
        float m1 = -3.402823466e+38f, m2 = -3.402823466e+38f;
        for (int i = 0; i < 64; ++i) {
            if (smask[i]) {
                m1 = fmaxf(m1, o1[(size_t)spos[i]*(NB*DDIM) + b*DDIM + dd]);
                m2 = fmaxf(m2, o2[(size_t)i      *(NB*DDIM) + b*DDIM + dd]);
            }
        }
        e1h[b*DDIM + dd] = has ? m1 : 0.0f;
        e2h[b*DDIM + dd] = has ? m2 : 0.0f;
    }
}

// ---------------------------------------------------------------------------
extern "C" void kernel_launch(void* const* d_in, const int* in_sizes, int n_in,
                              void* d_out, int out_size, void* d_ws, size_t ws_size,
                              hipStream_t stream)
{
    (void)in_sizes; (void)n_in; (void)out_size; (void)ws_size;
    const int*   t1    = (const int*)d_in[0];
    const int*   t2    = (const int*)d_in[1];
    const float* emb   = (const float*)d_in[2];
    const float* wih_f = (const float*)d_in[3];
    const float* whh_f = (const float*)d_in[4];
    const float* bih_f = (const float*)d_in[5];
    const float* bhh_f = (const float*)d_in[6];
    const float* wih_b = (const float*)d_in[7];
    const float* whh_b = (const float*)d_in[8];
    const float* bih_b = (const float*)d_in[9];
    const float* bhh_b = (const float*)d_in[10];
    float* out = (float*)d_out;

    char* ws = (char*)d_ws;
    size_t off = 0;
    auto carve = [&](size_t bytes) -> void* {
        void* p = ws + off;
        off = (off + bytes + 255) & ~(size_t)255;
        return p;
    };
    float*  o1    = (float*)carve(sizeof(float)*(size_t)L_SEQ*NB*DDIM);
    float*  o2    = (float*)carve(sizeof(float)*(size_t)L_SEQ*NB*DDIM);
    bf16_t* whhB  = (bf16_t*)carve(sizeof(bf16_t)*2*1024*HID);
    bf16_t* Bw    = (bf16_t*)carve(sizeof(bf16_t)*(size_t)NCOL*EMBD);
    float*  bias  = (float*)carve(sizeof(float)*NCOL);
    bf16_t* xgT   = (bf16_t*)carve(sizeof(bf16_t)*(size_t)MTOT*NCOL);  // 67 MB
    bf16_t* A     = (bf16_t*)o1;   // A dead before scan writes o1

    hipFuncSetAttribute((const void*)lstm_scan8,
                        hipFuncAttributeMaxDynamicSharedMemorySize, 147456);

    hipLaunchKernelGGL(k_pack_a, dim3(4096), dim3(256), 0, stream, t1, t2, emb, A);
    hipLaunchKernelGGL(k_pack_w, dim3(776),  dim3(256), 0, stream,
                       wih_f, wih_b, whh_f, whh_b,
                       bih_f, bhh_f, bih_b, bhh_b, Bw, whhB, bias);

    hipLaunchKernelGGL(xg_gemm4, dim3(16, 128), dim3(256), 0, stream, A, Bw, bias, xgT);

    hipLaunchKernelGGL(lstm_scan8, dim3(8, 4), dim3(1024), 147456, stream,
                       whhB, xgT, o1, o2);

    hipLaunchKernelGGL(k_att,    dim3(128), dim3(256), 0, stream, o1, o2, out);
    hipLaunchKernelGGL(k_common, dim3(128), dim3(256), 0, stream,
                       t1, t2, o1, o2, out + NB, out + NB + NB*DDIM);
}